// Round 2
// baseline (146.429 us; speedup 1.0000x reference)
//
#include <hip/hip_runtime.h>

#define A_N 192
#define D_N 576
#define W_N 384

// ---------------- conv1: sino [1,1,192,576] -> h [16,192,576], 5x5 pad=2 ----
__global__ void conv1_kernel(const float* __restrict__ sino,
                             const float* __restrict__ w1,
                             const float* __restrict__ b1,
                             float* __restrict__ h) {
    __shared__ float sw[400];
    __shared__ float sb[16];
    int tid = threadIdx.x;
    for (int i = tid; i < 400; i += 256) sw[i] = w1[i];
    if (tid < 16) sb[tid] = b1[tid];
    __syncthreads();
    int idx = blockIdx.x * blockDim.x + tid;
    if (idx >= A_N * D_N) return;
    int y = idx / D_N;
    int x = idx - y * D_N;
    float in[5][5];
    #pragma unroll
    for (int dy = 0; dy < 5; ++dy) {
        int yy = y + dy - 2;
        #pragma unroll
        for (int dx = 0; dx < 5; ++dx) {
            int xx = x + dx - 2;
            in[dy][dx] = (yy >= 0 && yy < A_N && xx >= 0 && xx < D_N)
                       ? sino[yy * D_N + xx] : 0.0f;
        }
    }
    #pragma unroll
    for (int c = 0; c < 16; ++c) {
        float acc = sb[c];
        #pragma unroll
        for (int dy = 0; dy < 5; ++dy)
            #pragma unroll
            for (int dx = 0; dx < 5; ++dx)
                acc = fmaf(in[dy][dx], sw[c * 25 + dy * 5 + dx], acc);
        h[c * (A_N * D_N) + idx] = acc;
    }
}

// ---------------- conv2: h [16,192,576] -> sino_pred [1,192,576], 5x5 pad=2 -
__global__ void conv2_kernel(const float* __restrict__ h,
                             const float* __restrict__ w2,
                             const float* __restrict__ b2,
                             float* __restrict__ out) {
    __shared__ float sw[400];
    int tid = threadIdx.x;
    for (int i = tid; i < 400; i += 256) sw[i] = w2[i];
    __syncthreads();
    int idx = blockIdx.x * blockDim.x + tid;
    if (idx >= A_N * D_N) return;
    int y = idx / D_N;
    int x = idx - y * D_N;
    float acc = b2[0];
    for (int c = 0; c < 16; ++c) {
        const float* hc = h + c * (A_N * D_N);
        #pragma unroll
        for (int dy = 0; dy < 5; ++dy) {
            int yy = y + dy - 2;
            if (yy < 0 || yy >= A_N) continue;
            #pragma unroll
            for (int dx = 0; dx < 5; ++dx) {
                int xx = x + dx - 2;
                if (xx >= 0 && xx < D_N)
                    acc = fmaf(hc[yy * D_N + xx], sw[c * 25 + dy * 5 + dx], acc);
            }
        }
    }
    out[idx] = acc;
}

// ---------------- fan-beam backprojection: [192,576] -> [384,384] ----------
// s = px*576/(576+py) + 287.5 ; linear interp along detector, zero outside.
__global__ void backproject_kernel(const float* __restrict__ sino0,
                                   const float* __restrict__ sino1,
                                   const float* __restrict__ angles,
                                   float* __restrict__ img0,
                                   float* __restrict__ img1) {
    __shared__ float cs[A_N];
    __shared__ float sn[A_N];
    int tid = threadIdx.x;
    if (tid < A_N) {
        float s, c;
        sincosf(angles[tid], &s, &c);
        cs[tid] = c;
        sn[tid] = s;
    }
    __syncthreads();
    const float* __restrict__ src = blockIdx.z ? sino1 : sino0;
    float* __restrict__ dst = blockIdx.z ? img1 : img0;
    int idx = blockIdx.x * blockDim.x + tid;
    if (idx >= W_N * W_N) return;
    int y = idx / W_N;
    int x = idx - y * W_N;
    float X = (float)x - 191.5f;
    float Y = (float)y - 191.5f;
    float acc = 0.0f;
    for (int a = 0; a < A_N; ++a) {
        float cb = cs[a], sb = sn[a];
        float px = fmaf(cb, X, sb * Y);
        float py = fmaf(cb, Y, -sb * X);
        float s  = fmaf(px, 576.0f / (576.0f + py), 287.5f);
        float fl = floorf(s);
        int   i0 = (int)fl;
        float fr = s - fl;
        int   i1 = i0 + 1;
        float w0 = (i0 >= 0 && i0 < D_N) ? (1.0f - fr) : 0.0f;
        float w1 = (i1 >= 0 && i1 < D_N) ? fr : 0.0f;
        int i0c = min(max(i0, 0), D_N - 1);
        int i1c = min(max(i1, 0), D_N - 1);
        const float* row = src + a * D_N;
        acc = fmaf(row[i0c], w0, acc);
        acc = fmaf(row[i1c], w1, acc);
    }
    dst[idx] = acc;
}

// ---------------- conv3: concat(img, img_sino) [2,384,384] -> [1,384,384] ---
__global__ void conv3_kernel(const float* __restrict__ img0,
                             const float* __restrict__ img1,
                             const float* __restrict__ w3,
                             const float* __restrict__ b3,
                             float* __restrict__ out) {
    __shared__ float sw[18];
    int tid = threadIdx.x;
    if (tid < 18) sw[tid] = w3[tid];
    __syncthreads();
    int idx = blockIdx.x * blockDim.x + tid;
    if (idx >= W_N * W_N) return;
    int y = idx / W_N;
    int x = idx - y * W_N;
    float acc = b3[0];
    #pragma unroll
    for (int dy = 0; dy < 3; ++dy) {
        int yy = y + dy - 1;
        if (yy < 0 || yy >= W_N) continue;
        #pragma unroll
        for (int dx = 0; dx < 3; ++dx) {
            int xx = x + dx - 1;
            if (xx < 0 || xx >= W_N) continue;
            acc = fmaf(img0[yy * W_N + xx], sw[dy * 3 + dx], acc);
            acc = fmaf(img1[yy * W_N + xx], sw[9 + dy * 3 + dx], acc);
        }
    }
    out[idx] = acc;
}

extern "C" void kernel_launch(void* const* d_in, const int* in_sizes, int n_in,
                              void* d_out, int out_size, void* d_ws, size_t ws_size,
                              hipStream_t stream) {
    const float* sino   = (const float*)d_in[0];
    const float* angles = (const float*)d_in[1];
    const float* w1     = (const float*)d_in[2];
    const float* b1     = (const float*)d_in[3];
    const float* w2     = (const float*)d_in[4];
    const float* b2     = (const float*)d_in[5];
    const float* w3     = (const float*)d_in[6];
    const float* b3     = (const float*)d_in[7];

    float* out       = (float*)d_out;
    float* sino_pred = out;                       // 192*576   = 110592
    float* img_sino  = out + A_N * D_N;           // 384*384   = 147456
    float* img_pred  = img_sino + W_N * W_N;      // 384*384   = 147456

    float* h   = (float*)d_ws;                    // 16*192*576 floats
    float* img = h + 16 * A_N * D_N;              // 384*384 floats

    dim3 blk(256);
    int nS = A_N * D_N;      // 110592 -> 432 blocks
    int nI = W_N * W_N;      // 147456 -> 576 blocks

    conv1_kernel<<<dim3((nS + 255) / 256), blk, 0, stream>>>(sino, w1, b1, h);
    conv2_kernel<<<dim3((nS + 255) / 256), blk, 0, stream>>>(h, w2, b2, sino_pred);
    backproject_kernel<<<dim3((nI + 255) / 256, 1, 2), blk, 0, stream>>>(
        sino, sino_pred, angles, img, img_sino);
    conv3_kernel<<<dim3((nI + 255) / 256), blk, 0, stream>>>(
        img, img_sino, w3, b3, img_pred);
}

// Round 3
// 105.413 us; speedup vs baseline: 1.3891x; 1.3891x over previous
//
#include <hip/hip_runtime.h>

#define A_N 192
#define D_N 576
#define W_N 384

// ---- fused conv1+conv2: sino [192,576] -> sino_pred [192,576] --------------
// conv2(conv1(x)) with zero padding. Interior pixels: collapsed 9x9 kernel
// W_eff. Boundary band (4 px): exact double sum with domain checks (conv1's
// output is zero-padded OUTSIDE the domain, so fused taps that leave and
// re-enter the domain must be handled exactly).
__global__ __launch_bounds__(256) void conv9_kernel(
    const float* __restrict__ sino,
    const float* __restrict__ w1, const float* __restrict__ b1,
    const float* __restrict__ w2, const float* __restrict__ b2,
    float* __restrict__ out)
{
    __shared__ float sw1[400], sw2[400], sb1[16];
    __shared__ float K[625];     // K[q*25+r] = sum_c w2[c,q]*w1[c,r]
    __shared__ float Weff[81];   // 9x9 collapsed kernel
    __shared__ float wsb1[25];   // sum_c w2[c,q]*b1[c]
    __shared__ float cons;       // b2 + sum_q wsb1[q]
    int tid = threadIdx.x;
    for (int i = tid; i < 400; i += 256) { sw1[i] = w1[i]; sw2[i] = w2[i]; }
    if (tid < 16) sb1[tid] = b1[tid];
    __syncthreads();
    for (int i = tid; i < 625; i += 256) {
        int q = i / 25, r = i - q * 25;
        float acc = 0.f;
        #pragma unroll
        for (int c = 0; c < 16; ++c)
            acc = fmaf(sw2[c * 25 + q], sw1[c * 25 + r], acc);
        K[i] = acc;
    }
    if (tid < 25) {
        float acc = 0.f;
        #pragma unroll
        for (int c = 0; c < 16; ++c) acc = fmaf(sw2[c * 25 + tid], sb1[c], acc);
        wsb1[tid] = acc;
    }
    __syncthreads();
    if (tid < 81) {
        int sy = tid / 9 - 4, sx = tid % 9 - 4;
        float acc = 0.f;
        #pragma unroll
        for (int uy = -2; uy <= 2; ++uy)
            #pragma unroll
            for (int ux = -2; ux <= 2; ++ux) {
                int vy = sy - uy, vx = sx - ux;
                if (vy >= -2 && vy <= 2 && vx >= -2 && vx <= 2)
                    acc += K[((uy + 2) * 5 + ux + 2) * 25 + (vy + 2) * 5 + vx + 2];
            }
        Weff[tid] = acc;
    }
    if (tid == 0) {
        float s = b2[0];
        for (int u = 0; u < 25; ++u) s += wsb1[u];
        cons = s;
    }
    __syncthreads();

    int idx = blockIdx.x * 256 + tid;
    if (idx >= A_N * D_N) return;
    int y = idx / D_N;
    int x = idx - y * D_N;

    if (y >= 4 && y <= A_N - 5 && x >= 4 && x <= D_N - 5) {
        // interior: 81-tap collapsed kernel, all taps in-domain
        const float* base = sino + idx;
        float acc = cons;
        #pragma unroll
        for (int sy = -4; sy <= 4; ++sy)
            #pragma unroll
            for (int sx = -4; sx <= 4; ++sx)
                acc = fmaf(base[sy * D_N + sx], Weff[(sy + 4) * 9 + sx + 4], acc);
        out[idx] = acc;
    } else {
        // boundary: exact two-stage composition
        float acc = b2[0];
        #pragma unroll
        for (int uy = -2; uy <= 2; ++uy) {
            int yy = y + uy;
            if (yy < 0 || yy >= A_N) continue;
            #pragma unroll
            for (int ux = -2; ux <= 2; ++ux) {
                int xx = x + ux;
                if (xx < 0 || xx >= D_N) continue;
                int u = (uy + 2) * 5 + ux + 2;
                float t = wsb1[u];
                #pragma unroll
                for (int vy = -2; vy <= 2; ++vy) {
                    int yyy = yy + vy;
                    if (yyy < 0 || yyy >= A_N) continue;
                    #pragma unroll
                    for (int vx = -2; vx <= 2; ++vx) {
                        int xxx = xx + vx;
                        if (xxx < 0 || xxx >= D_N) continue;
                        t = fmaf(K[u * 25 + (vy + 2) * 5 + vx + 2],
                                 sino[yyy * D_N + xxx], t);
                    }
                }
                acc += t;
            }
        }
        out[idx] = acc;
    }
}

// ---- dual fan-beam backprojection: sino0,sino1 [192,576] -> two [384,384] --
// Geometry shared between both images: one sincos table, one rcp, one
// floor/clamp per (pixel, angle); 4 gathers.
__global__ __launch_bounds__(256) void backproject2_kernel(
    const float* __restrict__ sino0, const float* __restrict__ sino1,
    const float* __restrict__ angles,
    float* __restrict__ img0, float* __restrict__ img1)
{
    __shared__ float cs[A_N];
    __shared__ float sn[A_N];
    int tid = threadIdx.x;
    if (tid < A_N) {
        float s, c;
        sincosf(angles[tid], &s, &c);
        cs[tid] = c;
        sn[tid] = s;
    }
    __syncthreads();
    int idx = blockIdx.x * 256 + tid;
    if (idx >= W_N * W_N) return;
    int y = idx / W_N;
    int x = idx - y * W_N;
    float X = (float)x - 191.5f;
    float Y = (float)y - 191.5f;
    float acc0 = 0.0f, acc1 = 0.0f;
    #pragma unroll 2
    for (int a = 0; a < A_N; ++a) {
        float cb = cs[a], sb = sn[a];
        float px = fmaf(cb, X, sb * Y);
        float py = fmaf(cb, Y, -sb * X);
        float inv = __builtin_amdgcn_rcpf(576.0f + py);   // py >= -272 > -576
        float s  = fmaf(px * 576.0f, inv, 287.5f);
        float fl = floorf(s);
        int   i0 = (int)fl;
        float fr = s - fl;
        int   i1 = i0 + 1;
        float w0 = (i0 >= 0 && i0 < D_N) ? (1.0f - fr) : 0.0f;
        float w1 = (i1 >= 0 && i1 < D_N) ? fr : 0.0f;
        int i0c = min(max(i0, 0), D_N - 1);
        int i1c = min(max(i1, 0), D_N - 1);
        const float* r0 = sino0 + a * D_N;
        const float* r1 = sino1 + a * D_N;
        acc0 = fmaf(r0[i0c], w0, acc0);
        acc0 = fmaf(r0[i1c], w1, acc0);
        acc1 = fmaf(r1[i0c], w0, acc1);
        acc1 = fmaf(r1[i1c], w1, acc1);
    }
    img0[idx] = acc0;
    img1[idx] = acc1;
}

// ---- conv3: concat(img, img_sino) [2,384,384] -> [1,384,384], 3x3 pad=1 ----
__global__ __launch_bounds__(256) void conv3_kernel(
    const float* __restrict__ img0, const float* __restrict__ img1,
    const float* __restrict__ w3, const float* __restrict__ b3,
    float* __restrict__ out)
{
    __shared__ float sw[18];
    int tid = threadIdx.x;
    if (tid < 18) sw[tid] = w3[tid];
    __syncthreads();
    int idx = blockIdx.x * 256 + tid;
    if (idx >= W_N * W_N) return;
    int y = idx / W_N;
    int x = idx - y * W_N;
    float acc = b3[0];
    #pragma unroll
    for (int dy = 0; dy < 3; ++dy) {
        int yy = y + dy - 1;
        if (yy < 0 || yy >= W_N) continue;
        #pragma unroll
        for (int dx = 0; dx < 3; ++dx) {
            int xx = x + dx - 1;
            if (xx < 0 || xx >= W_N) continue;
            acc = fmaf(img0[yy * W_N + xx], sw[dy * 3 + dx], acc);
            acc = fmaf(img1[yy * W_N + xx], sw[9 + dy * 3 + dx], acc);
        }
    }
    out[idx] = acc;
}

extern "C" void kernel_launch(void* const* d_in, const int* in_sizes, int n_in,
                              void* d_out, int out_size, void* d_ws, size_t ws_size,
                              hipStream_t stream) {
    const float* sino   = (const float*)d_in[0];
    const float* angles = (const float*)d_in[1];
    const float* w1     = (const float*)d_in[2];
    const float* b1     = (const float*)d_in[3];
    const float* w2     = (const float*)d_in[4];
    const float* b2     = (const float*)d_in[5];
    const float* w3     = (const float*)d_in[6];
    const float* b3     = (const float*)d_in[7];

    float* out       = (float*)d_out;
    float* sino_pred = out;                       // 192*576
    float* img_sino  = out + A_N * D_N;           // 384*384
    float* img_pred  = img_sino + W_N * W_N;      // 384*384

    float* img = (float*)d_ws;                    // 384*384 scratch

    int nS = A_N * D_N;      // 110592 -> 432 blocks
    int nI = W_N * W_N;      // 147456 -> 576 blocks

    conv9_kernel<<<dim3((nS + 255) / 256), dim3(256), 0, stream>>>(
        sino, w1, b1, w2, b2, sino_pred);
    backproject2_kernel<<<dim3((nI + 255) / 256), dim3(256), 0, stream>>>(
        sino, sino_pred, angles, img, img_sino);
    conv3_kernel<<<dim3((nI + 255) / 256), dim3(256), 0, stream>>>(
        img, img_sino, w3, b3, img_pred);
}

// Round 4
// 78.821 us; speedup vs baseline: 1.8578x; 1.3374x over previous
//
#include <hip/hip_runtime.h>

#define A_N 192
#define D_N 576
#define W_N 384

// ---- fused conv1+conv2 via LDS-tiled collapsed kernel ----------------------
// Block = 8x64 output tile; LDS holds zero-padded 16x72 input halo tile.
// Interior pixels: 81-tap collapsed kernel Weff. Boundary band (<=4px from
// edge): exact two-stage composition; zero-padded LDS makes inner-tap domain
// checks free, only the [p+q in domain] check on the conv2 tap remains.
#define TBY 8
#define TBX 64
#define THY (TBY + 8)
#define THX (TBX + 8)

__global__ __launch_bounds__(256) void conv9_kernel(
    const float* __restrict__ sino,
    const float* __restrict__ w1, const float* __restrict__ b1,
    const float* __restrict__ w2, const float* __restrict__ b2,
    float* __restrict__ out)
{
    __shared__ float t[THY][THX];          // zero-padded input tile
    __shared__ float sw1[400], sw2[400], sb1[16];
    __shared__ float K[625];               // K[q*25+r] = sum_c w2[c,q]*w1[c,r]
    __shared__ float Weff[81];             // collapsed 9x9
    __shared__ float wsb1[25];             // sum_c w2[c,q]*b1[c]
    __shared__ float cons;                 // b2 + sum_q wsb1[q]
    __shared__ float bb2;

    int tid = threadIdx.x;
    int byi = blockIdx.x / (D_N / TBX);    // 0..23
    int bxi = blockIdx.x % (D_N / TBX);    // 0..8
    int y0 = byi * TBY, x0 = bxi * TBX;

    // stage input tile (zero-padded outside domain)
    for (int i = tid; i < THY * THX; i += 256) {
        int r = i / THX, c = i - r * THX;
        int gy = y0 - 4 + r, gx = x0 - 4 + c;
        t[r][c] = (gy >= 0 && gy < A_N && gx >= 0 && gx < D_N)
                ? sino[gy * D_N + gx] : 0.0f;
    }
    // stage weights
    for (int i = tid; i < 400; i += 256) { sw1[i] = w1[i]; sw2[i] = w2[i]; }
    if (tid < 16) sb1[tid] = b1[tid];
    if (tid == 0) bb2 = b2[0];
    __syncthreads();

    for (int i = tid; i < 625; i += 256) {
        int q = i / 25, r = i - q * 25;
        float acc = 0.f;
        #pragma unroll
        for (int c = 0; c < 16; ++c)
            acc = fmaf(sw2[c * 25 + q], sw1[c * 25 + r], acc);
        K[i] = acc;
    }
    if (tid < 25) {
        float acc = 0.f;
        #pragma unroll
        for (int c = 0; c < 16; ++c) acc = fmaf(sw2[c * 25 + tid], sb1[c], acc);
        wsb1[tid] = acc;
    }
    __syncthreads();
    if (tid < 81) {
        int sy = tid / 9 - 4, sx = tid % 9 - 4;
        float acc = 0.f;
        #pragma unroll
        for (int uy = -2; uy <= 2; ++uy)
            #pragma unroll
            for (int ux = -2; ux <= 2; ++ux) {
                int vy = sy - uy, vx = sx - ux;
                if (vy >= -2 && vy <= 2 && vx >= -2 && vx <= 2)
                    acc += K[((uy + 2) * 5 + ux + 2) * 25 + (vy + 2) * 5 + vx + 2];
            }
        Weff[tid] = acc;
    }
    if (tid == 0) {
        float s = bb2;
        for (int u = 0; u < 25; ++u) s += wsb1[u];
        cons = s;
    }
    __syncthreads();

    int lr0 = tid >> 6;                    // 0..3
    int lc  = tid & 63;                    // 0..63
    #pragma unroll
    for (int half = 0; half < 2; ++half) {
        int lr = lr0 + half * 4;           // 0..7
        int gy = y0 + lr, gx = x0 + lc;
        float acc;
        if (gy >= 4 && gy <= A_N - 5 && gx >= 4 && gx <= D_N - 5) {
            acc = cons;
            #pragma unroll
            for (int sy = 0; sy < 9; ++sy)
                #pragma unroll
                for (int sx = 0; sx < 9; ++sx)
                    acc = fmaf(t[lr + sy][lc + sx], Weff[sy * 9 + sx], acc);
        } else {
            acc = bb2;
            #pragma unroll
            for (int qy = -2; qy <= 2; ++qy) {
                int gy2 = gy + qy;
                if (gy2 < 0 || gy2 >= A_N) continue;
                #pragma unroll
                for (int qx = -2; qx <= 2; ++qx) {
                    int gx2 = gx + qx;
                    if (gx2 < 0 || gx2 >= D_N) continue;
                    int u = (qy + 2) * 5 + qx + 2;
                    float ta = wsb1[u];
                    #pragma unroll
                    for (int vy = 0; vy < 5; ++vy)
                        #pragma unroll
                        for (int vx = 0; vx < 5; ++vx)
                            ta = fmaf(K[u * 25 + vy * 5 + vx],
                                      t[lr + 2 + qy + vy][lc + 2 + qx + vx], ta);
                    acc += ta;
                }
            }
        }
        out[gy * D_N + gx] = acc;
    }
}

// ---- dual fan-beam backprojection: sino0,sino1 [192,576] -> two [384,384] --
__global__ __launch_bounds__(256) void backproject2_kernel(
    const float* __restrict__ sino0, const float* __restrict__ sino1,
    const float* __restrict__ angles,
    float* __restrict__ img0, float* __restrict__ img1)
{
    __shared__ float cs[A_N];
    __shared__ float sn[A_N];
    int tid = threadIdx.x;
    if (tid < A_N) {
        float s, c;
        sincosf(angles[tid], &s, &c);
        cs[tid] = c;
        sn[tid] = s;
    }
    __syncthreads();
    int idx = blockIdx.x * 256 + tid;
    if (idx >= W_N * W_N) return;
    int y = idx / W_N;
    int x = idx - y * W_N;
    float X = (float)x - 191.5f;
    float Y = (float)y - 191.5f;
    float acc0 = 0.0f, acc1 = 0.0f;
    #pragma unroll 2
    for (int a = 0; a < A_N; ++a) {
        float cb = cs[a], sb = sn[a];
        float px = fmaf(cb, X, sb * Y);
        float py = fmaf(cb, Y, -sb * X);
        float inv = __builtin_amdgcn_rcpf(576.0f + py);   // py >= -272 > -576
        float s  = fmaf(px * 576.0f, inv, 287.5f);
        float fl = floorf(s);
        int   i0 = (int)fl;
        float fr = s - fl;
        int   i1 = i0 + 1;
        float w0 = (i0 >= 0 && i0 < D_N) ? (1.0f - fr) : 0.0f;
        float w1 = (i1 >= 0 && i1 < D_N) ? fr : 0.0f;
        int i0c = min(max(i0, 0), D_N - 1);
        int i1c = min(max(i1, 0), D_N - 1);
        const float* r0 = sino0 + a * D_N;
        const float* r1 = sino1 + a * D_N;
        acc0 = fmaf(r0[i0c], w0, acc0);
        acc0 = fmaf(r0[i1c], w1, acc0);
        acc1 = fmaf(r1[i0c], w0, acc1);
        acc1 = fmaf(r1[i1c], w1, acc1);
    }
    img0[idx] = acc0;
    img1[idx] = acc1;
}

// ---- conv3: concat(img, img_sino) [2,384,384] -> [1,384,384], 3x3 pad=1 ----
__global__ __launch_bounds__(256) void conv3_kernel(
    const float* __restrict__ img0, const float* __restrict__ img1,
    const float* __restrict__ w3, const float* __restrict__ b3,
    float* __restrict__ out)
{
    __shared__ float sw[18];
    int tid = threadIdx.x;
    if (tid < 18) sw[tid] = w3[tid];
    __syncthreads();
    int idx = blockIdx.x * 256 + tid;
    if (idx >= W_N * W_N) return;
    int y = idx / W_N;
    int x = idx - y * W_N;
    float acc = b3[0];
    #pragma unroll
    for (int dy = 0; dy < 3; ++dy) {
        int yy = y + dy - 1;
        if (yy < 0 || yy >= W_N) continue;
        #pragma unroll
        for (int dx = 0; dx < 3; ++dx) {
            int xx = x + dx - 1;
            if (xx < 0 || xx >= W_N) continue;
            acc = fmaf(img0[yy * W_N + xx], sw[dy * 3 + dx], acc);
            acc = fmaf(img1[yy * W_N + xx], sw[9 + dy * 3 + dx], acc);
        }
    }
    out[idx] = acc;
}

extern "C" void kernel_launch(void* const* d_in, const int* in_sizes, int n_in,
                              void* d_out, int out_size, void* d_ws, size_t ws_size,
                              hipStream_t stream) {
    const float* sino   = (const float*)d_in[0];
    const float* angles = (const float*)d_in[1];
    const float* w1     = (const float*)d_in[2];
    const float* b1     = (const float*)d_in[3];
    const float* w2     = (const float*)d_in[4];
    const float* b2     = (const float*)d_in[5];
    const float* w3     = (const float*)d_in[6];
    const float* b3     = (const float*)d_in[7];

    float* out       = (float*)d_out;
    float* sino_pred = out;                       // 192*576
    float* img_sino  = out + A_N * D_N;           // 384*384
    float* img_pred  = img_sino + W_N * W_N;      // 384*384

    float* img = (float*)d_ws;                    // 384*384 scratch

    int nI = W_N * W_N;      // 147456 -> 576 blocks
    int nBlocksConv9 = (A_N / TBY) * (D_N / TBX); // 24*9 = 216

    conv9_kernel<<<dim3(nBlocksConv9), dim3(256), 0, stream>>>(
        sino, w1, b1, w2, b2, sino_pred);
    backproject2_kernel<<<dim3((nI + 255) / 256), dim3(256), 0, stream>>>(
        sino, sino_pred, angles, img, img_sino);
    conv3_kernel<<<dim3((nI + 255) / 256), dim3(256), 0, stream>>>(
        img, img_sino, w3, b3, img_pred);
}

// Round 5
// 53.659 us; speedup vs baseline: 2.7289x; 1.4689x over previous
//
#include <hip/hip_runtime.h>

#define A_N 192
#define D_N 576
#define W_N 384
#define NPIX (W_N * W_N)   // 147456
#define NSIN (A_N * D_N)   // 110592

// ---- fused conv1+conv2 via 25 boundary-class collapsed 9x9 kernels ---------
// Exact: with zero-padded input tile, conv2(conv1(x)) == 81-tap collapsed
// kernel everywhere except the conv2 q-mask [p+q in domain], which depends
// only on the pixel's edge-distance class (5 y-classes x 5 x-classes).
// Also writes inter[idx] = (sino[idx], sino_pred[idx]) interleaved for the
// backprojection's dwordx2 gathers.
__global__ __launch_bounds__(256) void conv9_kernel(
    const float* __restrict__ sino,
    const float* __restrict__ w1, const float* __restrict__ b1,
    const float* __restrict__ w2, const float* __restrict__ b2,
    float* __restrict__ sino_pred, float2* __restrict__ inter)
{
    __shared__ float t[16][40];            // zero-padded 8x32 tile + 4 halo
    __shared__ float sw1[400], sw2[400], sb1[16];
    __shared__ float K[625], wsb1[25];
    __shared__ float Wc[25][81];           // class kernels
    __shared__ float biasc[25];

    int tid = threadIdx.x;
    int byi = blockIdx.x / 18;             // 576/32 = 18 tiles in x
    int bxi = blockIdx.x % 18;
    int y0 = byi * 8, x0 = bxi * 32;

    for (int i = tid; i < 640; i += 256) {
        int r = i / 40, c = i - r * 40;
        int gy = y0 - 4 + r, gx = x0 - 4 + c;
        t[r][c] = (gy >= 0 && gy < A_N && gx >= 0 && gx < D_N)
                ? sino[gy * D_N + gx] : 0.f;
    }
    for (int i = tid; i < 400; i += 256) { sw1[i] = w1[i]; sw2[i] = w2[i]; }
    if (tid < 16) sb1[tid] = b1[tid];
    __syncthreads();

    for (int i = tid; i < 625; i += 256) {
        int q = i / 25, r = i - q * 25;
        float acc = 0.f;
        #pragma unroll
        for (int c = 0; c < 16; ++c)
            acc = fmaf(sw2[c * 25 + q], sw1[c * 25 + r], acc);
        K[i] = acc;
    }
    if (tid < 25) {
        float acc = 0.f;
        #pragma unroll
        for (int c = 0; c < 16; ++c) acc = fmaf(sw2[c * 25 + tid], sb1[c], acc);
        wsb1[tid] = acc;
    }
    __syncthreads();

    // class kernels: Wc[cl][s] = sum over valid q of K[q][s-q]
    for (int e = tid; e < 2025; e += 256) {
        int cl = e / 81, s = e - cl * 81;
        int yc = cl / 5, xc = cl - yc * 5;
        int sy = s / 9 - 4, sx = s % 9 - 4;
        float acc = 0.f;
        for (int qy = -2; qy <= 2; ++qy) {
            if ((yc == 0 && qy < 0) || (yc == 1 && qy < -1) ||
                (yc == 3 && qy > 1) || (yc == 4 && qy > 0)) continue;
            int vy = sy - qy; if (vy < -2 || vy > 2) continue;
            for (int qx = -2; qx <= 2; ++qx) {
                if ((xc == 0 && qx < 0) || (xc == 1 && qx < -1) ||
                    (xc == 3 && qx > 1) || (xc == 4 && qx > 0)) continue;
                int vx = sx - qx; if (vx < -2 || vx > 2) continue;
                acc += K[((qy + 2) * 5 + qx + 2) * 25 + (vy + 2) * 5 + (vx + 2)];
            }
        }
        Wc[cl][s] = acc;
    }
    if (tid < 25) {
        int yc = tid / 5, xc = tid % 5;
        float acc = b2[0];
        for (int qy = -2; qy <= 2; ++qy) {
            if ((yc == 0 && qy < 0) || (yc == 1 && qy < -1) ||
                (yc == 3 && qy > 1) || (yc == 4 && qy > 0)) continue;
            for (int qx = -2; qx <= 2; ++qx) {
                if ((xc == 0 && qx < 0) || (xc == 1 && qx < -1) ||
                    (xc == 3 && qx > 1) || (xc == 4 && qx > 0)) continue;
                acc += wsb1[(qy + 2) * 5 + qx + 2];
            }
        }
        biasc[tid] = acc;
    }
    __syncthreads();

    int lr = tid >> 5, lc = tid & 31;
    int gy = y0 + lr, gx = x0 + lc;
    int yc = (gy <= 1) ? gy : ((gy >= A_N - 2) ? (gy - (A_N - 5)) : 2);
    int xc = (gx <= 1) ? gx : ((gx >= D_N - 2) ? (gx - (D_N - 5)) : 2);
    int cl = yc * 5 + xc;
    float acc = biasc[cl];
    const float* Wp = Wc[cl];
    #pragma unroll
    for (int sy = 0; sy < 9; ++sy)
        #pragma unroll
        for (int sx = 0; sx < 9; ++sx)
            acc = fmaf(t[lr + sy][lc + sx], Wp[sy * 9 + sx], acc);
    int gidx = gy * D_N + gx;
    sino_pred[gidx] = acc;
    inter[gidx] = make_float2(t[lr + 4][lc + 4], acc);
}

// ---- dual fan-beam backprojection, angle-split x2, dwordx2 gathers ---------
// part layout: [img 0/1][half 0/1][NPIX]
__global__ __launch_bounds__(256) void backproject2_kernel(
    const float2* __restrict__ inter,
    const float* __restrict__ angles,
    float* __restrict__ part)
{
    __shared__ float cs[96], sn[96];
    int tid = threadIdx.x;
    int half = blockIdx.y;
    int a0 = half * 96;
    if (tid < 96) {
        float s, c;
        sincosf(angles[a0 + tid], &s, &c);
        cs[tid] = c; sn[tid] = s;
    }
    __syncthreads();
    int idx = blockIdx.x * 256 + tid;
    int y = idx / W_N;
    int x = idx - y * W_N;
    float X = (float)x - 191.5f;
    float Y = (float)y - 191.5f;
    // R<=255 => detector coord s in [1.7, 573.3]: no masks/clamps needed.
    bool safe = (X * X + Y * Y) <= 255.0f * 255.0f;
    float acc0 = 0.f, acc1 = 0.f;
    for (int i = 0; i < 96; ++i) {
        float cb = cs[i], sb = sn[i];
        float px = fmaf(cb, X, sb * Y);
        float py = fmaf(cb, Y, -sb * X);
        float inv = __builtin_amdgcn_rcpf(576.0f + py);   // py >= -272
        float s  = fmaf(px * 576.0f, inv, 287.5f);
        float fl = floorf(s);
        float fr = s - fl;
        int i0 = (int)fl;
        int i1 = i0 + 1;
        float w0 = 1.0f - fr, w1 = fr;
        if (!safe) {
            w0 = ((unsigned)i0 < 576u) ? w0 : 0.f;
            w1 = ((unsigned)i1 < 576u) ? w1 : 0.f;
            i0 = min(max(i0, 0), 575);
            i1 = min(max(i1, 0), 575);
        }
        const float2* row = inter + (a0 + i) * D_N;
        float2 v0 = row[i0];
        float2 v1 = row[i1];
        acc0 = fmaf(v0.x, w0, acc0);
        acc0 = fmaf(v1.x, w1, acc0);
        acc1 = fmaf(v0.y, w0, acc1);
        acc1 = fmaf(v1.y, w1, acc1);
    }
    part[half * NPIX + idx]            = acc0;   // img (bp of sino)
    part[(2 + half) * NPIX + idx]      = acc1;   // img_sino (bp of sino_pred)
}

// ---- fused partial-sum + conv3: writes img_sino and img_pred ---------------
__global__ __launch_bounds__(256) void conv3_kernel(
    const float* __restrict__ part,
    const float* __restrict__ w3, const float* __restrict__ b3,
    float* __restrict__ img_sino, float* __restrict__ img_pred)
{
    __shared__ float t0[10][34], t1[10][34];
    __shared__ float sw[18];
    int tid = threadIdx.x;
    int byi = blockIdx.x / 12, bxi = blockIdx.x % 12;   // 384/32=12, 384/8=48
    int y0 = byi * 8, x0 = bxi * 32;
    const float* p0a = part;
    const float* p0b = part + NPIX;
    const float* p1a = part + 2 * NPIX;
    const float* p1b = part + 3 * NPIX;
    for (int i = tid; i < 340; i += 256) {
        int r = i / 34, c = i - r * 34;
        int gy = y0 - 1 + r, gx = x0 - 1 + c;
        bool in = (gy >= 0 && gy < W_N && gx >= 0 && gx < W_N);
        int g = gy * W_N + gx;
        t0[r][c] = in ? p0a[g] + p0b[g] : 0.f;
        t1[r][c] = in ? p1a[g] + p1b[g] : 0.f;
    }
    if (tid < 18) sw[tid] = w3[tid];
    __syncthreads();
    int lr = tid >> 5, lc = tid & 31;
    int gy = y0 + lr, gx = x0 + lc;
    int g = gy * W_N + gx;
    img_sino[g] = t1[lr + 1][lc + 1];
    float acc = b3[0];
    #pragma unroll
    for (int dy = 0; dy < 3; ++dy)
        #pragma unroll
        for (int dx = 0; dx < 3; ++dx) {
            acc = fmaf(t0[lr + dy][lc + dx], sw[dy * 3 + dx], acc);
            acc = fmaf(t1[lr + dy][lc + dx], sw[9 + dy * 3 + dx], acc);
        }
    img_pred[g] = acc;
}

extern "C" void kernel_launch(void* const* d_in, const int* in_sizes, int n_in,
                              void* d_out, int out_size, void* d_ws, size_t ws_size,
                              hipStream_t stream) {
    const float* sino   = (const float*)d_in[0];
    const float* angles = (const float*)d_in[1];
    const float* w1     = (const float*)d_in[2];
    const float* b1     = (const float*)d_in[3];
    const float* w2     = (const float*)d_in[4];
    const float* b2     = (const float*)d_in[5];
    const float* w3     = (const float*)d_in[6];
    const float* b3     = (const float*)d_in[7];

    float* out       = (float*)d_out;
    float* sino_pred = out;                       // 110592
    float* img_sino  = out + NSIN;                // 147456
    float* img_pred  = img_sino + NPIX;           // 147456

    float2* inter = (float2*)d_ws;                // NSIN float2
    float*  part  = (float*)d_ws + 2 * NSIN;      // 4 * NPIX floats

    conv9_kernel<<<dim3(432), dim3(256), 0, stream>>>(
        sino, w1, b1, w2, b2, sino_pred, inter);
    backproject2_kernel<<<dim3(576, 2), dim3(256), 0, stream>>>(
        inter, angles, part);
    conv3_kernel<<<dim3(576), dim3(256), 0, stream>>>(
        part, w3, b3, img_sino, img_pred);
}